// Round 18
// baseline (97.242 us; speedup 1.0000x reference)
//
#include <hip/hip_runtime.h>
#include <cstdint>

typedef unsigned short ushort_t;
typedef __attribute__((ext_vector_type(4))) float f32x4;
typedef __attribute__((ext_vector_type(8))) __bf16 bf16x8;
typedef __attribute__((ext_vector_type(8))) unsigned short ushort8;

#define NB 16384
#define DK 1024   // IN + H

#define MFMA16(a, b, c) __builtin_amdgcn_mfma_f32_16x16x32_bf16(a, b, c, 0, 0, 0)

__device__ __forceinline__ unsigned short f2b(float f) {
    unsigned u = __builtin_bit_cast(unsigned, f);
    unsigned r = u + 0x7fffu + ((u >> 16) & 1u);
    return (unsigned short)(r >> 16);
}
__device__ __forceinline__ float b2f(ushort_t b) {
    unsigned u = ((unsigned)b) << 16;
    return __builtin_bit_cast(float, u);
}
__device__ __forceinline__ float fast_sigmoid(float x) {
    return __fdividef(1.0f, 1.0f + __expf(-x));
}
__device__ __forceinline__ float fast_tanh(float x) {
    return __fdividef(2.0f, 1.0f + __expf(-2.0f * x)) - 1.0f;
}

__device__ __forceinline__ void gll16(const void* g, void* lds) {
    __builtin_amdgcn_global_load_lds(
        (__attribute__((address_space(1))) unsigned int*)(uintptr_t)g,
        (__attribute__((address_space(3))) unsigned int*)(unsigned int)(uintptr_t)lds,
        16, 0, 0);
}

// ---------------- prep kernels (proven; sources PRE-SWIZZLED) ----------------
// within each 64-elem K-group of a row, logical elem c stored at c ^ ((row&7)<<3).

__global__ __launch_bounds__(256) void k_cvt(const float* __restrict__ x,
                                             const float* __restrict__ h,
                                             ushort_t* __restrict__ XB,
                                             ushort_t* __restrict__ HB) {
    int b = blockIdx.x;
    const float* s;
    ushort_t* d;
    if (b < 4096) { s = x; d = XB; } else { s = h; d = HB; b -= 4096; }
    size_t g = (size_t)b * 256 + threadIdx.x;
    const float* p = s + g * 8;
    f32x4 f0 = *(const f32x4*)p;
    f32x4 f1 = *(const f32x4*)(p + 4);
    ushort8 o;
#pragma unroll
    for (int j = 0; j < 4; ++j) { o[j] = f2b(f0[j]); o[j + 4] = f2b(f1[j]); }
    size_t fi = g * 8;
    int row = (int)(fi >> 9);
    int c = (int)(fi & 511);
    int swc = (c & ~63) | ((c & 63) ^ ((row & 7) << 3));
    *(ushort8*)(d + (size_t)row * 512 + swc) = o;
}

__global__ __launch_bounds__(256) void k_transpose_w(const float* __restrict__ Wi,
                                                     const float* __restrict__ Wo,
                                                     ushort_t* __restrict__ WTI,
                                                     ushort_t* __restrict__ WTO) {
    const int z = blockIdx.z;
    if (z == 1 && blockIdx.x >= 16) return;
    const float* W = (z == 0) ? Wi : Wo;
    ushort_t* Wt = (z == 0) ? WTI : WTO;
    const int ncols = (z == 0) ? 1024 : 512;
    __shared__ float tile[32][33];
    int n0 = blockIdx.x * 32, k0 = blockIdx.y * 32;
    int tx = threadIdx.x & 31, ty = threadIdx.x >> 5;
#pragma unroll
    for (int i = 0; i < 32; i += 8)
        tile[ty + i][tx] = W[(size_t)(k0 + ty + i) * ncols + n0 + tx];
    __syncthreads();
#pragma unroll
    for (int i = 0; i < 32; i += 8) {
        int n = n0 + ty + i;
        int k = k0 + tx;
        int kk = (k & ~63) | ((k & 63) ^ ((n & 7) << 3));
        Wt[(size_t)n * DK + kk] = f2b(tile[tx][ty + i]);
    }
}

// ---------------- GEMM 1: PURE paired GEMM (R16 8-phase), raw acc out ----------------
// Epilogue = raw bf16 stores of learn/forget pre-activations (linear layout).
// No HB gather, no transcendentals, no bias — all moved to k_gate.
__global__ __launch_bounds__(512, 1) void k_gemm1(
    const ushort_t* __restrict__ XB, const ushort_t* __restrict__ HB,
    const ushort_t* __restrict__ WT,
    ushort_t* __restrict__ LPre, ushort_t* __restrict__ FPre) {
    __shared__ ushort_t As[2][256 * 64];
    __shared__ ushort_t Bs[2][256 * 64];

    const int t = threadIdx.x;
    const int lane = t & 63;
    const int wid = t >> 6;
    const int wm = wid >> 2, wn = wid & 3;
    const int m0 = blockIdx.x * 256;
    const int n0p = blockIdx.y * 128;
    const int srow = t >> 3;
    const int scol = (t & 7) * 8;
    const int fr = lane & 15, fq = lane >> 4;
    const int xr = (fr & 7) << 3;

    f32x4 acc[8][4] = {};   // [m-frag][j0,j1 learn | j2,j3 forget]

#define STA(tile, r) do { \
        int kt_ = (tile) * 64; \
        int grow_ = m0 + 64 * (r) + srow; \
        const ushort_t* s_ = (kt_ < 512) ? XB + (size_t)grow_ * 512 + kt_ + scol \
                                         : HB + (size_t)grow_ * 512 + (kt_ - 512) + scol; \
        gll16(s_, &As[(tile) & 1][(64 * (r) + srow) * 64 + scol]); \
    } while (0)
#define STB(tile, r) do { \
        int kt_ = (tile) * 64; \
        int wrow_ = ((r) < 2) ? (n0p + 64 * (r) + srow) : (512 + n0p + 64 * ((r) - 2) + srow); \
        gll16(WT + (size_t)wrow_ * DK + kt_ + scol, &Bs[(tile) & 1][(64 * (r) + srow) * 64 + scol]); \
    } while (0)

    bf16x8 a[4][2], bL[2][2], bF[2][2];

#define LDA(cb, mh) do { \
        _Pragma("unroll") for (int ii = 0; ii < 4; ++ii) \
        _Pragma("unroll") for (int kk = 0; kk < 2; ++kk) \
            a[ii][kk] = *(const bf16x8*)&As[cb][(wm * 128 + ((mh) * 4 + ii) * 16 + fr) * 64 + ((kk * 32 + fq * 8) ^ xr)]; \
    } while (0)
#define LDBL(cb) do { \
        _Pragma("unroll") for (int j = 0; j < 2; ++j) \
        _Pragma("unroll") for (int kk = 0; kk < 2; ++kk) \
            bL[j][kk] = *(const bf16x8*)&Bs[cb][(wn * 32 + j * 16 + fr) * 64 + ((kk * 32 + fq * 8) ^ xr)]; \
    } while (0)
#define LDBF(cb) do { \
        _Pragma("unroll") for (int j = 0; j < 2; ++j) \
        _Pragma("unroll") for (int kk = 0; kk < 2; ++kk) \
            bF[j][kk] = *(const bf16x8*)&Bs[cb][(128 + wn * 32 + j * 16 + fr) * 64 + ((kk * 32 + fq * 8) ^ xr)]; \
    } while (0)
#define MML(mh) do { \
        __builtin_amdgcn_s_setprio(1); \
        _Pragma("unroll") for (int kk = 0; kk < 2; ++kk) \
        _Pragma("unroll") for (int ii = 0; ii < 4; ++ii) \
        _Pragma("unroll") for (int j = 0; j < 2; ++j) \
            acc[(mh) * 4 + ii][j] = MFMA16(a[ii][kk], bL[j][kk], acc[(mh) * 4 + ii][j]); \
        __builtin_amdgcn_s_setprio(0); \
    } while (0)
#define MMF(mh) do { \
        __builtin_amdgcn_s_setprio(1); \
        _Pragma("unroll") for (int kk = 0; kk < 2; ++kk) \
        _Pragma("unroll") for (int ii = 0; ii < 4; ++ii) \
        _Pragma("unroll") for (int j = 0; j < 2; ++j) \
            acc[(mh) * 4 + ii][2 + j] = MFMA16(a[ii][kk], bF[j][kk], acc[(mh) * 4 + ii][2 + j]); \
        __builtin_amdgcn_s_setprio(0); \
    } while (0)
#define BAR asm volatile("s_barrier" ::: "memory")
#define VM2 asm volatile("s_waitcnt vmcnt(2)" ::: "memory")
#define VM0 asm volatile("s_waitcnt vmcnt(0)" ::: "memory")
#define LGKM0 do { asm volatile("s_waitcnt lgkmcnt(0)" ::: "memory"); __builtin_amdgcn_sched_barrier(0); } while (0)

    STA(0, 0); STA(0, 2);
    STA(0, 1); STA(0, 3);
    STB(0, 0); STB(0, 1);
    STB(0, 2); STB(0, 3);
    STA(1, 0); STA(1, 2);
    STA(1, 1); STA(1, 3);

    for (int i = 0; i < 8; ++i) {
        // tile 2i in dbuf 0 (even), tile 2i+1 in dbuf 1 — CONSTANT (R10 fix).
        const int g = (i < 7);
        const int t1 = 2 * i + 1, t2 = 2 * i + 2, t3 = 2 * i + 3;
        VM2; BAR;
        STB(t1, 0); STB(t1, 1);
        LDA(0, 0); LDBL(0);
        LGKM0; MML(0);
        BAR;
        if (g) { STA(t2, 0); STA(t2, 2); }
        LDBF(0);
        LGKM0; MMF(0);
        BAR;
        STB(t1, 2); STB(t1, 3);
        LDA(0, 1);
        LGKM0; MML(1);
        BAR;
        if (g) { STA(t2, 1); STA(t2, 3); }
        LGKM0; MMF(1);
        if (g) { VM2; } else { VM0; }
        BAR;
        if (g) { STB(t2, 0); STB(t2, 1); }
        LDA(1, 0); LDBL(1);
        LGKM0; MML(0);
        BAR;
        if (g) { STA(t3, 0); STA(t3, 2); }
        LDBF(1);
        LGKM0; MMF(0);
        BAR;
        if (g) { STB(t2, 2); STB(t2, 3); }
        LDA(1, 1);
        LGKM0; MML(1);
        BAR;
        if (g) { STA(t3, 1); STA(t3, 3); }
        LGKM0; MMF(1);
    }

    // raw epilogue: linear [row][c] bf16 stores, no math
#pragma unroll
    for (int mf = 0; mf < 8; ++mf)
#pragma unroll
        for (int j = 0; j < 2; ++j) {
            const int cp = n0p + wn * 32 + j * 16 + fr;
#pragma unroll
            for (int rr = 0; rr < 4; ++rr) {
                const int row = m0 + wm * 128 + mf * 16 + fq * 4 + rr;
                LPre[(size_t)row * 512 + cp] = f2b(acc[mf][j][rr]);
                FPre[(size_t)row * 512 + cp] = f2b(acc[mf][2 + j][rr]);
            }
        }
}

// ---------------- gate: elementwise, vectorized, memory-bound ----------------
// 1 thread = 8 cols of one row. Reads LPre/FPre bf16x8 + h f32; writes hnew f32
// (linear, output) + HN bf16 (PRE-SWIZZLED for gemm2's gll16 staging).
__global__ __launch_bounds__(256) void k_gate(
    const ushort_t* __restrict__ LPre, const ushort_t* __restrict__ FPre,
    const float* __restrict__ h, const float* __restrict__ b_in,
    float* __restrict__ hnew, ushort_t* __restrict__ HN) {
    size_t g = (size_t)blockIdx.x * 256 + threadIdx.x;   // 16384*64 threads
    const int row = (int)(g >> 6);
    const int c = (int)(g & 63) * 8;
    const size_t base = (size_t)row * 512 + c;

    ushort8 lp8 = *(const ushort8*)&LPre[base];
    ushort8 fp8 = *(const ushort8*)&FPre[base];
    f32x4 h0 = *(const f32x4*)&h[base];
    f32x4 h1 = *(const f32x4*)&h[base + 4];
    f32x4 bl0 = *(const f32x4*)&b_in[c];
    f32x4 bl1 = *(const f32x4*)&b_in[c + 4];
    f32x4 bf0 = *(const f32x4*)&b_in[512 + c];
    f32x4 bf1 = *(const f32x4*)&b_in[512 + c + 4];

    f32x4 o0, o1;
    ushort8 hn8;
#pragma unroll
    for (int i = 0; i < 8; ++i) {
        float lp = b2f(lp8[i]) + ((i < 4) ? bl0[i] : bl1[i - 4]);
        float fp = b2f(fp8[i]) + ((i < 4) ? bf0[i] : bf1[i - 4]);
        float hv = (i < 4) ? h0[i] : h1[i - 4];
        float fm = fast_sigmoid(fp);
        float lr = fast_tanh(lp);
        float hn = lr + fm * (hv - lr);
        if (i < 4) o0[i] = hn; else o1[i - 4] = hn;
        hn8[i] = f2b(hn);
    }
    *(f32x4*)&hnew[base] = o0;
    *(f32x4*)&hnew[base + 4] = o1;
    const int swc = (c & ~63) | ((c & 63) ^ ((row & 7) << 3));
    *(ushort8*)&HN[(size_t)row * 512 + swc] = hn8;
}

// ---------------- GEMM 2: out = tanh([x,h_new] @ W_out + b_out)  (proven) ----------------
__global__ __launch_bounds__(256, 2) void k_gemm2(
    const ushort_t* __restrict__ XB, const ushort_t* __restrict__ HN,
    const ushort_t* __restrict__ WT, const float* __restrict__ b_out,
    float* __restrict__ out) {
    __shared__ ushort_t A2[2][128 * 64];
    __shared__ ushort_t B2[2][128 * 64];

    const int wg = blockIdx.x;
    const int xcd = wg & 7, q = wg >> 3;
    const int m0 = ((xcd << 4) | (q & 15)) * 128;
    const int n0 = (q >> 4) * 128;

    const int t = threadIdx.x;
    const int lane = t & 63;
    const int wave = t >> 6;
    const int wm = wave >> 1, wn = wave & 1;

    f32x4 acc[4][4] = {};

    const int srow = t >> 3;
    const int skel = (t & 7) * 8;
    const ushort_t* gB = WT + (size_t)(n0 + srow) * DK + skel;
    const int fr = lane & 15;
    const int fq = lane >> 4;
    const int xr = (fr & 7) << 3;

    auto stage = [&](int it, int buf) {
        const int kt = it * 64;
        const ushort_t* ab = (kt < 512)
            ? (XB + (size_t)(m0 + srow) * 512 + kt + skel)
            : (HN + (size_t)(m0 + srow) * 512 + (kt - 512) + skel);
        ushort_t* a = &A2[buf][t * 8];
        ushort_t* b = &B2[buf][t * 8];
#pragma unroll
        for (int r = 0; r < 4; ++r) {
            gll16(ab + (size_t)(32 * r) * 512, a + 2048 * r);
            gll16(gB + kt + (size_t)(32 * r) * DK, b + 2048 * r);
        }
    };

    stage(0, 0);
    for (int it = 0; it < 16; ++it) {
        asm volatile("s_waitcnt vmcnt(0)" ::: "memory");
        __syncthreads();
        if (it + 1 < 16) stage(it + 1, (it + 1) & 1);
        const int cur = it & 1;
#pragma unroll
        for (int kk = 0; kk < 2; ++kk) {
            bf16x8 av[4], bv[4];
#pragma unroll
            for (int i = 0; i < 4; ++i) {
                av[i] = *(const bf16x8*)(&A2[cur][(wm * 64 + i * 16 + fr) * 64 + ((kk * 32 + fq * 8) ^ xr)]);
                bv[i] = *(const bf16x8*)(&B2[cur][(wn * 64 + i * 16 + fr) * 64 + ((kk * 32 + fq * 8) ^ xr)]);
            }
            __builtin_amdgcn_s_setprio(1);
#pragma unroll
            for (int i = 0; i < 4; ++i)
#pragma unroll
                for (int j = 0; j < 4; ++j)
                    acc[i][j] = MFMA16(av[i], bv[j], acc[i][j]);
            __builtin_amdgcn_s_setprio(0);
        }
    }

#pragma unroll
    for (int i = 0; i < 4; ++i)
#pragma unroll
        for (int j = 0; j < 4; ++j) {
            const int c = n0 + wn * 64 + j * 16 + fr;
            const float bo = b_out[c];
#pragma unroll
            for (int rr = 0; rr < 4; ++rr) {
                const int row = m0 + wm * 64 + i * 16 + fq * 4 + rr;
                out[(size_t)row * 512 + c] = fast_tanh(acc[i][j][rr] + bo);
            }
        }
}

extern "C" void kernel_launch(void* const* d_in, const int* in_sizes, int n_in,
                              void* d_out, int out_size, void* d_ws, size_t ws_size,
                              hipStream_t stream) {
    const float* x = (const float*)d_in[0];
    const float* h = (const float*)d_in[1];
    const float* W_in = (const float*)d_in[2];
    const float* b_in = (const float*)d_in[3];
    const float* W_out = (const float*)d_in[4];
    const float* b_out = (const float*)d_in[5];

    float* out = (float*)d_out;                    // [16384][512]
    float* hnew = out + (size_t)NB * 512;          // [16384][512]

    // workspace: XB,HB,HN,LPre,FPre bf16 16MB each + WTI 2MB + WTO 1MB = 83MB
    ushort_t* XB = (ushort_t*)d_ws;
    ushort_t* HB = XB + (size_t)NB * 512;
    ushort_t* HN = HB + (size_t)NB * 512;
    ushort_t* LPre = HN + (size_t)NB * 512;
    ushort_t* FPre = LPre + (size_t)NB * 512;
    ushort_t* WTI = FPre + (size_t)NB * 512;
    ushort_t* WTO = WTI + (size_t)1024 * 1024;

    k_cvt<<<8192, 256, 0, stream>>>(x, h, XB, HB);
    k_transpose_w<<<dim3(32, 32, 2), 256, 0, stream>>>(W_in, W_out, WTI, WTO);
    k_gemm1<<<dim3(64, 4), 512, 0, stream>>>(XB, HB, WTI, LPre, FPre);
    k_gate<<<4096, 256, 0, stream>>>(LPre, FPre, h, b_in, hnew, HN);
    k_gemm2<<<512, 256, 0, stream>>>(XB, HN, WTO, b_out, out);
}

// Round 19
// 83.023 us; speedup vs baseline: 1.1713x; 1.1713x over previous
//
#include <hip/hip_runtime.h>
#include <cstdint>

typedef unsigned short ushort_t;
typedef __attribute__((ext_vector_type(4))) float f32x4;
typedef __attribute__((ext_vector_type(8))) __bf16 bf16x8;
typedef __attribute__((ext_vector_type(8))) unsigned short ushort8;

#define NB 16384
#define DK 1024   // IN + H

#define MFMA16(a, b, c) __builtin_amdgcn_mfma_f32_16x16x32_bf16(a, b, c, 0, 0, 0)

__device__ __forceinline__ unsigned short f2b(float f) {
    unsigned u = __builtin_bit_cast(unsigned, f);
    unsigned r = u + 0x7fffu + ((u >> 16) & 1u);
    return (unsigned short)(r >> 16);
}
__device__ __forceinline__ float b2f(ushort_t b) {
    unsigned u = ((unsigned)b) << 16;
    return __builtin_bit_cast(float, u);
}
__device__ __forceinline__ float fast_sigmoid(float x) {
    return __fdividef(1.0f, 1.0f + __expf(-x));
}
__device__ __forceinline__ float fast_tanh(float x) {
    return __fdividef(2.0f, 1.0f + __expf(-2.0f * x)) - 1.0f;
}

__device__ __forceinline__ void gll16(const void* g, void* lds) {
    __builtin_amdgcn_global_load_lds(
        (__attribute__((address_space(1))) unsigned int*)(uintptr_t)g,
        (__attribute__((address_space(3))) unsigned int*)(unsigned int)(uintptr_t)lds,
        16, 0, 0);
}

// ---------------- prep: cvt + W-transposes MERGED into one launch ----------------
// Sources PRE-SWIZZLED: within each 64-elem K-group of a row, elem c stored at
// c ^ ((row&7)<<3)  (R6-verified: LDS bank conflicts -> 0).
// blocks [0,8192): cvt x/h -> XB/HB ; [8192,9216): W_in^T ; [9216,9728): W_out^T.
__global__ __launch_bounds__(256) void k_prep(
    const float* __restrict__ x, const float* __restrict__ h,
    const float* __restrict__ Wi, const float* __restrict__ Wo,
    ushort_t* __restrict__ XB, ushort_t* __restrict__ HB,
    ushort_t* __restrict__ WTI, ushort_t* __restrict__ WTO) {
    __shared__ float tile[32][33];
    int b = blockIdx.x;
    if (b < 8192) {
        const float* s;
        ushort_t* d;
        if (b < 4096) { s = x; d = XB; } else { s = h; d = HB; b -= 4096; }
        size_t g = (size_t)b * 256 + threadIdx.x;
        const float* p = s + g * 8;
        f32x4 f0 = *(const f32x4*)p;
        f32x4 f1 = *(const f32x4*)(p + 4);
        ushort8 o;
#pragma unroll
        for (int j = 0; j < 4; ++j) { o[j] = f2b(f0[j]); o[j + 4] = f2b(f1[j]); }
        size_t fi = g * 8;
        int row = (int)(fi >> 9);
        int c = (int)(fi & 511);
        int swc = (c & ~63) | ((c & 63) ^ ((row & 7) << 3));
        *(ushort8*)(d + (size_t)row * 512 + swc) = o;
        return;
    }
    b -= 8192;
    const float* W;
    ushort_t* Wt;
    int ncols, n0, k0;
    if (b < 1024) { W = Wi; Wt = WTI; ncols = 1024; n0 = (b & 31) * 32; k0 = (b >> 5) * 32; }
    else { b -= 1024; W = Wo; Wt = WTO; ncols = 512; n0 = (b & 15) * 32; k0 = (b >> 4) * 32; }
    int tx = threadIdx.x & 31, ty = threadIdx.x >> 5;
#pragma unroll
    for (int i = 0; i < 32; i += 8)
        tile[ty + i][tx] = W[(size_t)(k0 + ty + i) * ncols + n0 + tx];
    __syncthreads();
#pragma unroll
    for (int i = 0; i < 32; i += 8) {
        int n = n0 + ty + i;
        int k = k0 + tx;
        int kk = (k & ~63) | ((k & 63) ^ ((n & 7) << 3));
        Wt[(size_t)n * DK + kk] = f2b(tile[tx][ty + i]);
    }
}

// ---------------- GEMM 1: 8-phase paired, fused gate epilogue (R11, 52-53us) ----------------
__global__ __launch_bounds__(512, 1) void k_gemm1(
    const ushort_t* __restrict__ XB, const ushort_t* __restrict__ HB,
    const ushort_t* __restrict__ WT, const float* __restrict__ b_in,
    float* __restrict__ hnew, ushort_t* __restrict__ HN) {
    __shared__ ushort_t As[2][256 * 64];
    __shared__ ushort_t Bs[2][256 * 64];

    const int t = threadIdx.x;
    const int lane = t & 63;
    const int wid = t >> 6;
    const int wm = wid >> 2, wn = wid & 3;
    const int m0 = blockIdx.x * 256;
    const int n0p = blockIdx.y * 128;
    const int srow = t >> 3;
    const int scol = (t & 7) * 8;
    const int fr = lane & 15, fq = lane >> 4;
    const int xr = (fr & 7) << 3;

    f32x4 acc[8][4] = {};   // [m-frag][j0,j1 learn | j2,j3 forget]

#define STA(tile, r) do { \
        int kt_ = (tile) * 64; \
        int grow_ = m0 + 64 * (r) + srow; \
        const ushort_t* s_ = (kt_ < 512) ? XB + (size_t)grow_ * 512 + kt_ + scol \
                                         : HB + (size_t)grow_ * 512 + (kt_ - 512) + scol; \
        gll16(s_, &As[(tile) & 1][(64 * (r) + srow) * 64 + scol]); \
    } while (0)
#define STB(tile, r) do { \
        int kt_ = (tile) * 64; \
        int wrow_ = ((r) < 2) ? (n0p + 64 * (r) + srow) : (512 + n0p + 64 * ((r) - 2) + srow); \
        gll16(WT + (size_t)wrow_ * DK + kt_ + scol, &Bs[(tile) & 1][(64 * (r) + srow) * 64 + scol]); \
    } while (0)

    bf16x8 a[4][2], bL[2][2], bF[2][2];

#define LDA(cb, mh) do { \
        _Pragma("unroll") for (int ii = 0; ii < 4; ++ii) \
        _Pragma("unroll") for (int kk = 0; kk < 2; ++kk) \
            a[ii][kk] = *(const bf16x8*)&As[cb][(wm * 128 + ((mh) * 4 + ii) * 16 + fr) * 64 + ((kk * 32 + fq * 8) ^ xr)]; \
    } while (0)
#define LDBL(cb) do { \
        _Pragma("unroll") for (int j = 0; j < 2; ++j) \
        _Pragma("unroll") for (int kk = 0; kk < 2; ++kk) \
            bL[j][kk] = *(const bf16x8*)&Bs[cb][(wn * 32 + j * 16 + fr) * 64 + ((kk * 32 + fq * 8) ^ xr)]; \
    } while (0)
#define LDBF(cb) do { \
        _Pragma("unroll") for (int j = 0; j < 2; ++j) \
        _Pragma("unroll") for (int kk = 0; kk < 2; ++kk) \
            bF[j][kk] = *(const bf16x8*)&Bs[cb][(128 + wn * 32 + j * 16 + fr) * 64 + ((kk * 32 + fq * 8) ^ xr)]; \
    } while (0)
#define MML(mh) do { \
        __builtin_amdgcn_s_setprio(1); \
        _Pragma("unroll") for (int kk = 0; kk < 2; ++kk) \
        _Pragma("unroll") for (int ii = 0; ii < 4; ++ii) \
        _Pragma("unroll") for (int j = 0; j < 2; ++j) \
            acc[(mh) * 4 + ii][j] = MFMA16(a[ii][kk], bL[j][kk], acc[(mh) * 4 + ii][j]); \
        __builtin_amdgcn_s_setprio(0); \
    } while (0)
#define MMF(mh) do { \
        __builtin_amdgcn_s_setprio(1); \
        _Pragma("unroll") for (int kk = 0; kk < 2; ++kk) \
        _Pragma("unroll") for (int ii = 0; ii < 4; ++ii) \
        _Pragma("unroll") for (int j = 0; j < 2; ++j) \
            acc[(mh) * 4 + ii][2 + j] = MFMA16(a[ii][kk], bF[j][kk], acc[(mh) * 4 + ii][2 + j]); \
        __builtin_amdgcn_s_setprio(0); \
    } while (0)
#define BAR asm volatile("s_barrier" ::: "memory")
#define VM2 asm volatile("s_waitcnt vmcnt(2)" ::: "memory")
#define VM0 asm volatile("s_waitcnt vmcnt(0)" ::: "memory")
#define LGKM0 do { asm volatile("s_waitcnt lgkmcnt(0)" ::: "memory"); __builtin_amdgcn_sched_barrier(0); } while (0)

    STA(0, 0); STA(0, 2);
    STA(0, 1); STA(0, 3);
    STB(0, 0); STB(0, 1);
    STB(0, 2); STB(0, 3);
    STA(1, 0); STA(1, 2);
    STA(1, 1); STA(1, 3);

    for (int i = 0; i < 8; ++i) {
        // tile 2i in dbuf 0 (even), tile 2i+1 in dbuf 1 — CONSTANT (R10 fix).
        const int g = (i < 7);
        const int t1 = 2 * i + 1, t2 = 2 * i + 2, t3 = 2 * i + 3;
        VM2; BAR;
        STB(t1, 0); STB(t1, 1);
        LDA(0, 0); LDBL(0);
        LGKM0; MML(0);
        BAR;
        if (g) { STA(t2, 0); STA(t2, 2); }
        LDBF(0);
        LGKM0; MMF(0);
        BAR;
        STB(t1, 2); STB(t1, 3);
        LDA(0, 1);
        LGKM0; MML(1);
        BAR;
        if (g) { STA(t2, 1); STA(t2, 3); }
        LGKM0; MMF(1);
        if (g) { VM2; } else { VM0; }
        BAR;
        if (g) { STB(t2, 0); STB(t2, 1); }
        LDA(1, 0); LDBL(1);
        LGKM0; MML(0);
        BAR;
        if (g) { STA(t3, 0); STA(t3, 2); }
        LDBF(1);
        LGKM0; MMF(0);
        BAR;
        if (g) { STB(t2, 2); STB(t2, 3); }
        LDA(1, 1);
        LGKM0; MML(1);
        BAR;
        if (g) { STA(t3, 1); STA(t3, 3); }
        LGKM0; MMF(1);
    }

    // fused gate epilogue: C/D map col=lane&15, row=(lane>>4)*4+reg
#pragma unroll
    for (int mf = 0; mf < 8; ++mf)
#pragma unroll
        for (int j = 0; j < 2; ++j) {
            const int cp = n0p + wn * 32 + j * 16 + fr;
            const float bl = b_in[cp];
            const float bf = b_in[cp + 512];
#pragma unroll
            for (int rr = 0; rr < 4; ++rr) {
                const int row = m0 + wm * 128 + mf * 16 + fq * 4 + rr;
                const int sc = (cp & ~63) | ((cp & 63) ^ ((row & 7) << 3));
                float lp = acc[mf][j][rr] + bl;
                float fp = acc[mf][2 + j][rr] + bf;
                float hv = b2f(HB[(size_t)row * 512 + sc]);
                float fm = fast_sigmoid(fp);
                float lr = fast_tanh(lp);
                float hn = lr + fm * (hv - lr);
                hnew[(size_t)row * 512 + cp] = hn;
                HN[(size_t)row * 512 + sc] = f2b(hn);
            }
        }
}

// ---------------- GEMM 2: out = tanh([x,h_new] @ W_out + b_out)  (R11, ~16us) ----------------
__global__ __launch_bounds__(256, 2) void k_gemm2(
    const ushort_t* __restrict__ XB, const ushort_t* __restrict__ HN,
    const ushort_t* __restrict__ WT, const float* __restrict__ b_out,
    float* __restrict__ out) {
    __shared__ ushort_t A2[2][128 * 64];
    __shared__ ushort_t B2[2][128 * 64];

    const int wg = blockIdx.x;                // 0..511, XCD-pinned
    const int xcd = wg & 7, q = wg >> 3;
    const int m0 = ((xcd << 4) | (q & 15)) * 128;
    const int n0 = (q >> 4) * 128;

    const int t = threadIdx.x;
    const int lane = t & 63;
    const int wave = t >> 6;
    const int wm = wave >> 1, wn = wave & 1;

    f32x4 acc[4][4] = {};

    const int srow = t >> 3;
    const int skel = (t & 7) * 8;
    const ushort_t* gB = WT + (size_t)(n0 + srow) * DK + skel;
    const int fr = lane & 15;
    const int fq = lane >> 4;
    const int xr = (fr & 7) << 3;

    auto stage = [&](int it, int buf) {
        const int kt = it * 64;
        const ushort_t* ab = (kt < 512)
            ? (XB + (size_t)(m0 + srow) * 512 + kt + skel)
            : (HN + (size_t)(m0 + srow) * 512 + (kt - 512) + skel);
        ushort_t* a = &A2[buf][t * 8];
        ushort_t* b = &B2[buf][t * 8];
#pragma unroll
        for (int r = 0; r < 4; ++r) {
            gll16(ab + (size_t)(32 * r) * 512, a + 2048 * r);
            gll16(gB + kt + (size_t)(32 * r) * DK, b + 2048 * r);
        }
    };

    stage(0, 0);
    for (int it = 0; it < 16; ++it) {
        asm volatile("s_waitcnt vmcnt(0)" ::: "memory");
        __syncthreads();
        if (it + 1 < 16) stage(it + 1, (it + 1) & 1);
        const int cur = it & 1;
#pragma unroll
        for (int kk = 0; kk < 2; ++kk) {
            bf16x8 av[4], bv[4];
#pragma unroll
            for (int i = 0; i < 4; ++i) {
                av[i] = *(const bf16x8*)(&A2[cur][(wm * 64 + i * 16 + fr) * 64 + ((kk * 32 + fq * 8) ^ xr)]);
                bv[i] = *(const bf16x8*)(&B2[cur][(wn * 64 + i * 16 + fr) * 64 + ((kk * 32 + fq * 8) ^ xr)]);
            }
            __builtin_amdgcn_s_setprio(1);
#pragma unroll
            for (int i = 0; i < 4; ++i)
#pragma unroll
                for (int j = 0; j < 4; ++j)
                    acc[i][j] = MFMA16(av[i], bv[j], acc[i][j]);
            __builtin_amdgcn_s_setprio(0);
        }
    }

#pragma unroll
    for (int i = 0; i < 4; ++i)
#pragma unroll
        for (int j = 0; j < 4; ++j) {
            const int c = n0 + wn * 64 + j * 16 + fr;
            const float bo = b_out[c];
#pragma unroll
            for (int rr = 0; rr < 4; ++rr) {
                const int row = m0 + wm * 64 + i * 16 + fq * 4 + rr;
                out[(size_t)row * 512 + c] = fast_tanh(acc[i][j][rr] + bo);
            }
        }
}

extern "C" void kernel_launch(void* const* d_in, const int* in_sizes, int n_in,
                              void* d_out, int out_size, void* d_ws, size_t ws_size,
                              hipStream_t stream) {
    const float* x = (const float*)d_in[0];
    const float* h = (const float*)d_in[1];
    const float* W_in = (const float*)d_in[2];
    const float* b_in = (const float*)d_in[3];
    const float* W_out = (const float*)d_in[4];
    const float* b_out = (const float*)d_in[5];

    float* out = (float*)d_out;                    // [16384][512]
    float* hnew = out + (size_t)NB * 512;          // [16384][512]

    ushort_t* XB = (ushort_t*)d_ws;
    ushort_t* HB = XB + (size_t)NB * 512;
    ushort_t* HN = HB + (size_t)NB * 512;
    ushort_t* WTI = HN + (size_t)NB * 512;
    ushort_t* WTO = WTI + (size_t)1024 * 1024;

    k_prep<<<9728, 256, 0, stream>>>(x, h, W_in, W_out, XB, HB, WTI, WTO);
    k_gemm1<<<dim3(64, 4), 512, 0, stream>>>(XB, HB, WTI, b_in, hnew, HN);
    k_gemm2<<<512, 256, 0, stream>>>(XB, HN, WTO, b_out, out);
}